// Round 1
// baseline (4750.718 us; speedup 1.0000x reference)
//
#include <hip/hip_runtime.h>

#define N_FEAT 512
#define HID 16
#define NCLS 10
#define G2S 12  // padded row stride (floats) for g2 / out accumulator

typedef float4 f4;

// ---------------- degree / norm ----------------
__global__ void k_deg_init(float* __restrict__ dinv, int n) {
    int i = blockIdx.x * blockDim.x + threadIdx.x;
    if (i < n) dinv[i] = 1.0f;  // self-loop
}

__global__ void k_deg_count(const int* __restrict__ dst, float* __restrict__ deg, int E) {
    int e = blockIdx.x * blockDim.x + threadIdx.x;
    if (e < E) atomicAdd(&deg[dst[e]], 1.0f);
}

__global__ void k_dinv(float* __restrict__ dinv, int n) {
    int i = blockIdx.x * blockDim.x + threadIdx.x;
    if (i < n) dinv[i] = rsqrtf(dinv[i]);  // deg >= 1 always
}

// ---------------- layer-1 GEMM: h1 = x @ W1, fused g1 = h1*dinv, acc1 init = g1 ----------------
// 256 threads, 256-row tile, each thread 4 rows x 4 cols, K-chunks of 32 floats.
// LDS float4-granule layouts with rotate-swizzle to kill bank conflicts.
__global__ __launch_bounds__(256, 2)
void k_gemm1(const float* __restrict__ x, const float* __restrict__ W1,
             const float* __restrict__ dinv, float* __restrict__ g1,
             float* __restrict__ acc1, int n)
{
    __shared__ f4 wt4[16 * 128];   // Wt[col][kg] swizzled, 32 KB
    __shared__ f4 xs4[256 * 8];    // x tile [row][slot] swizzled, 32 KB

    const int t  = threadIdx.x;
    const int cg = t & 3;          // thread cols: cg, cg+4, cg+8, cg+12
    const int rg = t >> 2;         // thread rows: 4*rg .. 4*rg+3
    const int r0 = blockIdx.x * 256;

    // stage W transposed + swizzled: Wt[c][kg'] holds W[4kg..4kg+3][c]
    for (int idx = t; idx < 16 * N_FEAT; idx += 256) {
        int k = idx >> 4, c = idx & 15;          // coalesced read of W1[k][c]
        int kg = k >> 2, kj = k & 3;
        int kgp = (kg & ~7) | ((kg + c) & 7);
        ((float*)&wt4[c * 128 + kgp])[kj] = W1[idx];
    }

    float acc[4][4];
    #pragma unroll
    for (int a = 0; a < 4; ++a)
        #pragma unroll
        for (int b = 0; b < 4; ++b) acc[a][b] = 0.0f;

    for (int kc = 0; kc < N_FEAT / 32; ++kc) {
        __syncthreads();  // xs4 reuse barrier (also covers W staging on first iter)
        #pragma unroll
        for (int it = 0; it < 8; ++it) {
            int p = t + it * 256;           // physical granule 0..2047
            int row = p >> 3, slot = p & 7;
            int kgl = (slot - (row >> 2)) & 7;   // inverse swizzle
            int gr = r0 + row;
            f4 v = make_float4(0.f, 0.f, 0.f, 0.f);
            if (gr < n)
                v = *reinterpret_cast<const f4*>(&x[(size_t)gr * N_FEAT + kc * 32 + kgl * 4]);
            xs4[p] = v;
        }
        __syncthreads();

        #pragma unroll
        for (int kgl = 0; kgl < 8; ++kgl) {
            f4 xv[4], wv[4];
            #pragma unroll
            for (int ri = 0; ri < 4; ++ri)
                xv[ri] = xs4[(rg * 4 + ri) * 8 + ((kgl + rg) & 7)];
            int kgG = kc * 8 + kgl;
            #pragma unroll
            for (int ci = 0; ci < 4; ++ci) {
                int col = cg + 4 * ci;
                int kgp = (kgG & ~7) | ((kgG + col) & 7);
                wv[ci] = wt4[col * 128 + kgp];
            }
            #pragma unroll
            for (int ri = 0; ri < 4; ++ri)
                #pragma unroll
                for (int ci = 0; ci < 4; ++ci)
                    acc[ri][ci] += xv[ri].x * wv[ci].x + xv[ri].y * wv[ci].y
                                 + xv[ri].z * wv[ci].z + xv[ri].w * wv[ci].w;
        }
    }

    #pragma unroll
    for (int ri = 0; ri < 4; ++ri) {
        int r = r0 + rg * 4 + ri;
        if (r < n) {
            float dv = dinv[r];
            #pragma unroll
            for (int ci = 0; ci < 4; ++ci) {
                int col = cg + 4 * ci;
                float v = acc[ri][ci] * dv;    // fold dinv[src] into message
                g1[(size_t)r * HID + col] = v;
                acc1[(size_t)r * HID + col] = v;  // self-loop contribution
            }
        }
    }
}

// ---------------- layer-1 scatter: acc1[dst] += g1[src] ----------------
__global__ void k_scat1(const int* __restrict__ ei, const float* __restrict__ g1,
                        float* __restrict__ acc1, int E)
{
    int e = blockIdx.x * blockDim.x + threadIdx.x;
    if (e >= E) return;
    int s = ei[e], d = ei[E + e];
    const f4* gs = reinterpret_cast<const f4*>(&g1[(size_t)s * HID]);
    f4 v0 = gs[0], v1 = gs[1], v2 = gs[2], v3 = gs[3];
    float* o = &acc1[(size_t)d * HID];
    atomicAdd(o + 0,  v0.x); atomicAdd(o + 1,  v0.y); atomicAdd(o + 2,  v0.z); atomicAdd(o + 3,  v0.w);
    atomicAdd(o + 4,  v1.x); atomicAdd(o + 5,  v1.y); atomicAdd(o + 6,  v1.z); atomicAdd(o + 7,  v1.w);
    atomicAdd(o + 8,  v2.x); atomicAdd(o + 9,  v2.y); atomicAdd(o + 10, v2.z); atomicAdd(o + 11, v2.w);
    atomicAdd(o + 12, v3.x); atomicAdd(o + 13, v3.y); atomicAdd(o + 14, v3.z); atomicAdd(o + 15, v3.w);
}

// ---------------- mid: a = relu(dinv*acc1 + b1); h2 = a@W2; g2 = dinv*h2; oacc init = g2 ----------------
__global__ void k_mid(const float* __restrict__ acc1, const float* __restrict__ dinv,
                      const float* __restrict__ b1, const float* __restrict__ W2,
                      float* __restrict__ g2, float* __restrict__ oacc, int n)
{
    __shared__ float sW2[HID * NCLS];
    if (threadIdx.x < HID * NCLS) sW2[threadIdx.x] = W2[threadIdx.x];
    __syncthreads();
    int i = blockIdx.x * blockDim.x + threadIdx.x;
    if (i >= n) return;
    float dv = dinv[i];
    const f4* ap = reinterpret_cast<const f4*>(&acc1[(size_t)i * HID]);
    f4 a0 = ap[0], a1 = ap[1], a2 = ap[2], a3 = ap[3];
    float a[HID] = { a0.x, a0.y, a0.z, a0.w, a1.x, a1.y, a1.z, a1.w,
                     a2.x, a2.y, a2.z, a2.w, a3.x, a3.y, a3.z, a3.w };
    #pragma unroll
    for (int c = 0; c < HID; ++c)
        a[c] = fmaxf(dv * a[c] + b1[c], 0.0f);   // bias after aggregation, then relu
    float h2[NCLS];
    #pragma unroll
    for (int j = 0; j < NCLS; ++j) h2[j] = 0.0f;
    #pragma unroll
    for (int c = 0; c < HID; ++c)
        #pragma unroll
        for (int j = 0; j < NCLS; ++j)
            h2[j] += a[c] * sW2[c * NCLS + j];
    #pragma unroll
    for (int j = 0; j < NCLS; ++j) h2[j] *= dv;  // fold dinv[src]
    f4 w0 = make_float4(h2[0], h2[1], h2[2], h2[3]);
    f4 w1 = make_float4(h2[4], h2[5], h2[6], h2[7]);
    f4 w2 = make_float4(h2[8], h2[9], 0.0f, 0.0f);
    f4* gp = reinterpret_cast<f4*>(&g2[(size_t)i * G2S]);
    gp[0] = w0; gp[1] = w1; gp[2] = w2;
    f4* op = reinterpret_cast<f4*>(&oacc[(size_t)i * G2S]);
    op[0] = w0; op[1] = w1; op[2] = w2;          // self-loop contribution
}

// ---------------- layer-2 scatter ----------------
__global__ void k_scat2(const int* __restrict__ ei, const float* __restrict__ g2,
                        float* __restrict__ oacc, int E)
{
    int e = blockIdx.x * blockDim.x + threadIdx.x;
    if (e >= E) return;
    int s = ei[e], d = ei[E + e];
    const f4* gs = reinterpret_cast<const f4*>(&g2[(size_t)s * G2S]);
    f4 v0 = gs[0], v1 = gs[1], v2 = gs[2];
    float* o = &oacc[(size_t)d * G2S];
    atomicAdd(o + 0, v0.x); atomicAdd(o + 1, v0.y); atomicAdd(o + 2, v0.z); atomicAdd(o + 3, v0.w);
    atomicAdd(o + 4, v1.x); atomicAdd(o + 5, v1.y); atomicAdd(o + 6, v1.z); atomicAdd(o + 7, v1.w);
    atomicAdd(o + 8, v2.x); atomicAdd(o + 9, v2.y);
}

// ---------------- final: out = dinv*oacc + b2 ----------------
__global__ void k_final(const float* __restrict__ oacc, const float* __restrict__ dinv,
                        const float* __restrict__ b2, float* __restrict__ out, int tot)
{
    int idx = blockIdx.x * blockDim.x + threadIdx.x;
    if (idx >= tot) return;
    int i = idx / NCLS, j = idx - i * NCLS;
    out[idx] = dinv[i] * oacc[(size_t)i * G2S + j] + b2[j];
}

extern "C" void kernel_launch(void* const* d_in, const int* in_sizes, int n_in,
                              void* d_out, int out_size, void* d_ws, size_t ws_size,
                              hipStream_t stream) {
    const float* x  = (const float*)d_in[0];
    const int*   ei = (const int*)d_in[1];   // [2][E], int32 per harness convention
    const float* W1 = (const float*)d_in[2];
    const float* b1 = (const float*)d_in[3];
    const float* W2 = (const float*)d_in[4];
    const float* b2 = (const float*)d_in[5];
    float* out = (float*)d_out;

    const int n = in_sizes[0] / N_FEAT;   // 100000
    const int E = in_sizes[1] / 2;        // 3200000

    char* ws = (char*)d_ws;
    size_t off = 0;
    auto alloc = [&](size_t bytes) -> void* {
        void* p = ws + off;
        off = (off + bytes + 255) & ~(size_t)255;
        return p;
    };
    float* dinv = (float*)alloc((size_t)n * 4);
    float* g1   = (float*)alloc((size_t)n * HID * 4);
    float* acc1 = (float*)alloc((size_t)n * HID * 4);
    float* g2   = (float*)alloc((size_t)n * G2S * 4);
    float* oacc = (float*)alloc((size_t)n * G2S * 4);

    dim3 blk(256);
    int nb_n = (n + 255) / 256;
    int nb_e = (E + 255) / 256;

    k_deg_init<<<nb_n, blk, 0, stream>>>(dinv, n);
    k_deg_count<<<nb_e, blk, 0, stream>>>(ei + E, dinv, E);
    k_dinv<<<nb_n, blk, 0, stream>>>(dinv, n);
    k_gemm1<<<nb_n, blk, 0, stream>>>(x, W1, dinv, g1, acc1, n);
    k_scat1<<<nb_e, blk, 0, stream>>>(ei, g1, acc1, E);
    k_mid<<<nb_n, blk, 0, stream>>>(acc1, dinv, b1, W2, g2, oacc, n);
    k_scat2<<<nb_e, blk, 0, stream>>>(ei, g2, oacc, E);
    int tot = n * NCLS;
    k_final<<<(tot + 255) / 256, blk, 0, stream>>>(oacc, dinv, b2, out, tot);
}

// Round 2
// 898.062 us; speedup vs baseline: 5.2900x; 5.2900x over previous
//
#include <hip/hip_runtime.h>

#define N_FEAT 512
#define HID 16
#define NCLS 10
#define G2S 12  // padded row stride (floats) for g2

typedef float4 f4;

// ---------------- degree count (int atomics) ----------------
__global__ void k_deg_count(const int* __restrict__ dst, int* __restrict__ deg, int E) {
    int e = blockIdx.x * blockDim.x + threadIdx.x;
    if (e < E) atomicAdd(&deg[dst[e]], 1);
}

// ---------------- exclusive scan of deg -> row_off (3 kernels) ----------------
__global__ void k_scan1(const int* __restrict__ deg, int* __restrict__ row_off,
                        int* __restrict__ bsum, int n) {
    const int t = threadIdx.x;
    const int base = blockIdx.x * 1024 + t * 4;
    int v[4];
    #pragma unroll
    for (int j = 0; j < 4; ++j) v[j] = (base + j < n) ? deg[base + j] : 0;
    int tsum = v[0] + v[1] + v[2] + v[3];
    int inc = tsum;
    #pragma unroll
    for (int off = 1; off < 64; off <<= 1) {
        int u = __shfl_up(inc, off, 64);
        if ((t & 63) >= off) inc += u;
    }
    __shared__ int wsum[4];
    int w = t >> 6;
    if ((t & 63) == 63) wsum[w] = inc;
    __syncthreads();
    int wbase = 0;
    for (int k = 0; k < w; ++k) wbase += wsum[k];
    int run = wbase + inc - tsum;  // exclusive prefix of this thread's 4 elems
    #pragma unroll
    for (int j = 0; j < 4; ++j) {
        if (base + j < n) row_off[base + j] = run;
        run += v[j];
    }
    if (t == 255) bsum[blockIdx.x] = wbase + inc;  // block total
}

__global__ void k_scan2(int* __restrict__ bsum, int nb) {
    __shared__ int s[256];
    int t = threadIdx.x;
    if (t < nb) s[t] = bsum[t];
    __syncthreads();
    if (t == 0) {
        int run = 0;
        for (int k = 0; k < nb; ++k) { int v = s[k]; s[k] = run; run += v; }
    }
    __syncthreads();
    if (t < nb) bsum[t] = s[t];
}

// add block offsets; init cursor; compute dinv = rsqrt(deg+1)
__global__ void k_scan3(int* __restrict__ row_off, const int* __restrict__ bsum,
                        int* __restrict__ cursor, const int* __restrict__ deg,
                        float* __restrict__ dinv, int n) {
    int i = blockIdx.x * blockDim.x + threadIdx.x;
    if (i >= n) return;
    int ro = row_off[i] + bsum[i >> 10];
    row_off[i] = ro;
    cursor[i] = ro;
    dinv[i] = rsqrtf((float)deg[i] + 1.0f);
}

// ---------------- CSR fill ----------------
__global__ void k_fill(const int* __restrict__ ei, int* __restrict__ cursor,
                       int* __restrict__ csr, int E) {
    int e = blockIdx.x * blockDim.x + threadIdx.x;
    if (e >= E) return;
    int s = ei[e], d = ei[E + e];
    int pos = atomicAdd(&cursor[d], 1);
    csr[pos] = s;
}

// ---------------- layer-1 GEMM: g1 = (x @ W1) * dinv ----------------
__global__ __launch_bounds__(256, 2)
void k_gemm1(const float* __restrict__ x, const float* __restrict__ W1,
             const float* __restrict__ dinv, float* __restrict__ g1, int n)
{
    __shared__ f4 wt4[16 * 128];   // Wt[col][kg] swizzled
    __shared__ f4 xs4[256 * 8];    // x tile [row][slot] swizzled

    const int t  = threadIdx.x;
    const int cg = t & 3;
    const int rg = t >> 2;
    const int r0 = blockIdx.x * 256;

    for (int idx = t; idx < 16 * N_FEAT; idx += 256) {
        int k = idx >> 4, c = idx & 15;
        int kg = k >> 2, kj = k & 3;
        int kgp = (kg & ~7) | ((kg + c) & 7);
        ((float*)&wt4[c * 128 + kgp])[kj] = W1[idx];
    }

    float acc[4][4];
    #pragma unroll
    for (int a = 0; a < 4; ++a)
        #pragma unroll
        for (int b = 0; b < 4; ++b) acc[a][b] = 0.0f;

    for (int kc = 0; kc < N_FEAT / 32; ++kc) {
        __syncthreads();
        #pragma unroll
        for (int it = 0; it < 8; ++it) {
            int p = t + it * 256;
            int row = p >> 3, slot = p & 7;
            int kgl = (slot - (row >> 2)) & 7;
            int gr = r0 + row;
            f4 v = make_float4(0.f, 0.f, 0.f, 0.f);
            if (gr < n)
                v = *reinterpret_cast<const f4*>(&x[(size_t)gr * N_FEAT + kc * 32 + kgl * 4]);
            xs4[p] = v;
        }
        __syncthreads();

        #pragma unroll
        for (int kgl = 0; kgl < 8; ++kgl) {
            f4 xv[4], wv[4];
            #pragma unroll
            for (int ri = 0; ri < 4; ++ri)
                xv[ri] = xs4[(rg * 4 + ri) * 8 + ((kgl + rg) & 7)];
            int kgG = kc * 8 + kgl;
            #pragma unroll
            for (int ci = 0; ci < 4; ++ci) {
                int col = cg + 4 * ci;
                int kgp = (kgG & ~7) | ((kgG + col) & 7);
                wv[ci] = wt4[col * 128 + kgp];
            }
            #pragma unroll
            for (int ri = 0; ri < 4; ++ri)
                #pragma unroll
                for (int ci = 0; ci < 4; ++ci)
                    acc[ri][ci] += xv[ri].x * wv[ci].x + xv[ri].y * wv[ci].y
                                 + xv[ri].z * wv[ci].z + xv[ri].w * wv[ci].w;
        }
    }

    #pragma unroll
    for (int ri = 0; ri < 4; ++ri) {
        int r = r0 + rg * 4 + ri;
        if (r < n) {
            float dv = dinv[r];
            #pragma unroll
            for (int ci = 0; ci < 4; ++ci)
                g1[(size_t)r * HID + cg + 4 * ci] = acc[ri][ci] * dv;
        }
    }
}

// ---------------- layer-1 aggregation (gather): acc1[i] = g1[i] + sum_nbr g1[s] ----------------
__global__ void k_agg1(const int* __restrict__ row_off, const int* __restrict__ deg,
                       const int* __restrict__ csr, const float* __restrict__ g1,
                       float* __restrict__ acc1, int n)
{
    int tid = blockIdx.x * blockDim.x + threadIdx.x;
    int i = tid >> 2, lane = tid & 3;
    if (i >= n) return;
    size_t fo = (size_t)lane * 4;
    f4 acc = *reinterpret_cast<const f4*>(&g1[(size_t)i * HID + fo]);  // self-loop
    int beg = row_off[i], d = deg[i];
    for (int j = 0; j < d; ++j) {
        int s = csr[beg + j];
        f4 v = *reinterpret_cast<const f4*>(&g1[(size_t)s * HID + fo]);
        acc.x += v.x; acc.y += v.y; acc.z += v.z; acc.w += v.w;
    }
    *reinterpret_cast<f4*>(&acc1[(size_t)i * HID + fo]) = acc;
}

// ---------------- mid: a = relu(dinv*acc1 + b1); g2 = dinv*(a @ W2) ----------------
__global__ void k_mid(const float* __restrict__ acc1, const float* __restrict__ dinv,
                      const float* __restrict__ b1, const float* __restrict__ W2,
                      float* __restrict__ g2, int n)
{
    __shared__ float sW2[HID * NCLS];
    if (threadIdx.x < HID * NCLS) sW2[threadIdx.x] = W2[threadIdx.x];
    __syncthreads();
    int i = blockIdx.x * blockDim.x + threadIdx.x;
    if (i >= n) return;
    float dv = dinv[i];
    const f4* ap = reinterpret_cast<const f4*>(&acc1[(size_t)i * HID]);
    f4 a0 = ap[0], a1 = ap[1], a2 = ap[2], a3 = ap[3];
    float a[HID] = { a0.x, a0.y, a0.z, a0.w, a1.x, a1.y, a1.z, a1.w,
                     a2.x, a2.y, a2.z, a2.w, a3.x, a3.y, a3.z, a3.w };
    #pragma unroll
    for (int c = 0; c < HID; ++c)
        a[c] = fmaxf(dv * a[c] + b1[c], 0.0f);
    float h2[NCLS];
    #pragma unroll
    for (int j = 0; j < NCLS; ++j) h2[j] = 0.0f;
    #pragma unroll
    for (int c = 0; c < HID; ++c)
        #pragma unroll
        for (int j = 0; j < NCLS; ++j)
            h2[j] += a[c] * sW2[c * NCLS + j];
    f4 w0 = make_float4(dv * h2[0], dv * h2[1], dv * h2[2], dv * h2[3]);
    f4 w1 = make_float4(dv * h2[4], dv * h2[5], dv * h2[6], dv * h2[7]);
    f4 w2 = make_float4(dv * h2[8], dv * h2[9], 0.0f, 0.0f);
    f4* gp = reinterpret_cast<f4*>(&g2[(size_t)i * G2S]);
    gp[0] = w0; gp[1] = w1; gp[2] = w2;
}

// ---------------- layer-2 aggregation + final epilogue fused ----------------
__global__ void k_agg2(const int* __restrict__ row_off, const int* __restrict__ deg,
                       const int* __restrict__ csr, const float* __restrict__ g2,
                       const float* __restrict__ dinv, const float* __restrict__ b2,
                       float* __restrict__ out, int n)
{
    int tid = blockIdx.x * blockDim.x + threadIdx.x;
    int i = tid >> 2, lane = tid & 3;
    if (i >= n || lane >= 3) return;
    size_t fo = (size_t)lane * 4;
    f4 acc = *reinterpret_cast<const f4*>(&g2[(size_t)i * G2S + fo]);  // self-loop
    int beg = row_off[i], d = deg[i];
    for (int j = 0; j < d; ++j) {
        int s = csr[beg + j];
        f4 v = *reinterpret_cast<const f4*>(&g2[(size_t)s * G2S + fo]);
        acc.x += v.x; acc.y += v.y; acc.z += v.z; acc.w += v.w;
    }
    float dv = dinv[i];
    int col = lane * 4;
    float* o = &out[(size_t)i * NCLS + col];
    o[0] = dv * acc.x + b2[col + 0];
    o[1] = dv * acc.y + b2[col + 1];
    if (col + 2 < NCLS) {
        o[2] = dv * acc.z + b2[col + 2];
        o[3] = dv * acc.w + b2[col + 3];
    }
}

extern "C" void kernel_launch(void* const* d_in, const int* in_sizes, int n_in,
                              void* d_out, int out_size, void* d_ws, size_t ws_size,
                              hipStream_t stream) {
    const float* x  = (const float*)d_in[0];
    const int*   ei = (const int*)d_in[1];
    const float* W1 = (const float*)d_in[2];
    const float* b1 = (const float*)d_in[3];
    const float* W2 = (const float*)d_in[4];
    const float* b2 = (const float*)d_in[5];
    float* out = (float*)d_out;

    const int n = in_sizes[0] / N_FEAT;   // 100000
    const int E = in_sizes[1] / 2;        // 3200000

    char* ws = (char*)d_ws;
    size_t off = 0;
    auto alloc = [&](size_t bytes) -> void* {
        void* p = ws + off;
        off = (off + bytes + 255) & ~(size_t)255;
        return p;
    };
    int*   deg     = (int*)alloc((size_t)n * 4);
    int*   row_off = (int*)alloc((size_t)n * 4);
    int*   cursor  = (int*)alloc((size_t)n * 4);
    int*   bsum    = (int*)alloc(256 * 4);
    int*   csr     = (int*)alloc((size_t)E * 4);
    float* dinv    = (float*)alloc((size_t)n * 4);
    float* g1      = (float*)alloc((size_t)n * HID * 4);
    float* acc1    = (float*)alloc((size_t)n * HID * 4);
    float* g2      = (float*)alloc((size_t)n * G2S * 4);

    dim3 blk(256);
    int nb_n = (n + 255) / 256;
    int nb_e = (E + 255) / 256;
    int nb_scan = (n + 1023) / 1024;      // 98 blocks (<=256)

    hipMemsetAsync(deg, 0, (size_t)n * 4, stream);
    k_deg_count<<<nb_e, blk, 0, stream>>>(ei + E, deg, E);
    k_scan1<<<nb_scan, blk, 0, stream>>>(deg, row_off, bsum, n);
    k_scan2<<<1, blk, 0, stream>>>(bsum, nb_scan);
    k_scan3<<<nb_n, blk, 0, stream>>>(row_off, bsum, cursor, deg, dinv, n);
    k_fill<<<nb_e, blk, 0, stream>>>(ei, cursor, csr, E);
    k_gemm1<<<nb_n, blk, 0, stream>>>(x, W1, dinv, g1, n);
    int nb_a1 = (n * 4 + 255) / 256;
    k_agg1<<<nb_a1, blk, 0, stream>>>(row_off, deg, csr, g1, acc1, n);
    k_mid<<<nb_n, blk, 0, stream>>>(acc1, dinv, b1, W2, g2, n);
    k_agg2<<<nb_a1, blk, 0, stream>>>(row_off, deg, csr, g2, dinv, b2, out, n);
}

// Round 3
// 757.966 us; speedup vs baseline: 6.2677x; 1.1848x over previous
//
#include <hip/hip_runtime.h>

#define N_FEAT 512
#define HID 16
#define NCLS 10
#define G2S 12        // padded row stride (floats) for g2
#define CAP 64        // bucket capacity (max in-degree ~59 for Poisson(32) graph)
#define CAPW 6
#define OVF_CAP 65536

typedef float4 f4;

// ---------------- fused degree-count + CSR fill (fixed-stride buckets) ----------------
__global__ void k_fill(const int* __restrict__ ei, int* __restrict__ cnt,
                       int* __restrict__ csr, int* __restrict__ ovfc,
                       int* __restrict__ ovf, int E)
{
    int e0 = (blockIdx.x * blockDim.x + threadIdx.x) * 4;
    if (e0 >= E) return;
    int4 s4 = *reinterpret_cast<const int4*>(ei + e0);
    int4 d4 = *reinterpret_cast<const int4*>(ei + E + e0);
#define PROC(S, D, OK)                                                          \
    if (OK) {                                                                   \
        int j = atomicAdd(&cnt[D], 1);                                          \
        if (j < CAP) csr[((size_t)(D) << CAPW) + j] = (S);                      \
        else { int p = atomicAdd(ovfc, 1);                                      \
               if (p < OVF_CAP) { ovf[2 * p] = (S); ovf[2 * p + 1] = (D); } }   \
    }
    PROC(s4.x, d4.x, true)
    PROC(s4.y, d4.y, e0 + 1 < E)
    PROC(s4.z, d4.z, e0 + 2 < E)
    PROC(s4.w, d4.w, e0 + 3 < E)
#undef PROC
}

// ---------------- dinv = rsqrt(deg + 1) ----------------
__global__ void k_dinv(const int* __restrict__ cnt, float* __restrict__ dinv, int n) {
    int i = blockIdx.x * blockDim.x + threadIdx.x;
    if (i < n) dinv[i] = rsqrtf((float)cnt[i] + 1.0f);
}

// ---------------- layer-1 GEMM: g1 = (x @ W1) * dinv ----------------
__global__ __launch_bounds__(256, 2)
void k_gemm1(const float* __restrict__ x, const float* __restrict__ W1,
             const float* __restrict__ dinv, float* __restrict__ g1, int n)
{
    __shared__ f4 wt4[16 * 128];   // Wt[col][kg] swizzled
    __shared__ f4 xs4[256 * 8];    // x tile [row][slot] swizzled

    const int t  = threadIdx.x;
    const int cg = t & 3;
    const int rg = t >> 2;
    const int r0 = blockIdx.x * 256;

    for (int idx = t; idx < 16 * N_FEAT; idx += 256) {
        int k = idx >> 4, c = idx & 15;
        int kg = k >> 2, kj = k & 3;
        int kgp = (kg & ~7) | ((kg + c) & 7);
        ((float*)&wt4[c * 128 + kgp])[kj] = W1[idx];
    }

    float acc[4][4];
    #pragma unroll
    for (int a = 0; a < 4; ++a)
        #pragma unroll
        for (int b = 0; b < 4; ++b) acc[a][b] = 0.0f;

    for (int kc = 0; kc < N_FEAT / 32; ++kc) {
        __syncthreads();
        #pragma unroll
        for (int it = 0; it < 8; ++it) {
            int p = t + it * 256;
            int row = p >> 3, slot = p & 7;
            int kgl = (slot - (row >> 2)) & 7;
            int gr = r0 + row;
            f4 v = make_float4(0.f, 0.f, 0.f, 0.f);
            if (gr < n)
                v = *reinterpret_cast<const f4*>(&x[(size_t)gr * N_FEAT + kc * 32 + kgl * 4]);
            xs4[p] = v;
        }
        __syncthreads();

        #pragma unroll
        for (int kgl = 0; kgl < 8; ++kgl) {
            f4 xv[4], wv[4];
            #pragma unroll
            for (int ri = 0; ri < 4; ++ri)
                xv[ri] = xs4[(rg * 4 + ri) * 8 + ((kgl + rg) & 7)];
            int kgG = kc * 8 + kgl;
            #pragma unroll
            for (int ci = 0; ci < 4; ++ci) {
                int col = cg + 4 * ci;
                int kgp = (kgG & ~7) | ((kgG + col) & 7);
                wv[ci] = wt4[col * 128 + kgp];
            }
            #pragma unroll
            for (int ri = 0; ri < 4; ++ri)
                #pragma unroll
                for (int ci = 0; ci < 4; ++ci)
                    acc[ri][ci] += xv[ri].x * wv[ci].x + xv[ri].y * wv[ci].y
                                 + xv[ri].z * wv[ci].z + xv[ri].w * wv[ci].w;
        }
    }

    #pragma unroll
    for (int ri = 0; ri < 4; ++ri) {
        int r = r0 + rg * 4 + ri;
        if (r < n) {
            float dv = dinv[r];
            #pragma unroll
            for (int ci = 0; ci < 4; ++ci)
                g1[(size_t)r * HID + cg + 4 * ci] = acc[ri][ci] * dv;
        }
    }
}

// ---------------- fused layer-1 aggregation + mid transform ----------------
// 4 lanes per node; lane L owns features 4L..4L+3 of the aggregate, then the
// 16->10 GEMM is reduced across the 4 lanes via shfl_xor.
__global__ void k_aggmid(const int* __restrict__ cnt, const int* __restrict__ csr,
                         const float* __restrict__ g1, const float* __restrict__ dinv,
                         const float* __restrict__ b1, const float* __restrict__ W2,
                         const int* __restrict__ ovfc, const int* __restrict__ ovf,
                         float* __restrict__ g2, int n)
{
    __shared__ float sW2[HID * NCLS];
    if (threadIdx.x < HID * NCLS) sW2[threadIdx.x] = W2[threadIdx.x];
    __syncthreads();
    int tid = blockIdx.x * blockDim.x + threadIdx.x;
    int i = tid >> 2, L = tid & 3;
    if (i >= n) return;
    size_t fo = (size_t)L * 4;
    f4 acc = *reinterpret_cast<const f4*>(&g1[(size_t)i * HID + fo]);  // self-loop
    int d = cnt[i];
    int dc = d < CAP ? d : CAP;
    const int* bkt = &csr[(size_t)i << CAPW];
    int j = 0;
    for (; j + 4 <= dc; j += 4) {
        int4 sv = *reinterpret_cast<const int4*>(bkt + j);
        f4 v0 = *reinterpret_cast<const f4*>(&g1[(size_t)sv.x * HID + fo]);
        f4 v1 = *reinterpret_cast<const f4*>(&g1[(size_t)sv.y * HID + fo]);
        f4 v2 = *reinterpret_cast<const f4*>(&g1[(size_t)sv.z * HID + fo]);
        f4 v3 = *reinterpret_cast<const f4*>(&g1[(size_t)sv.w * HID + fo]);
        acc.x += (v0.x + v1.x) + (v2.x + v3.x);
        acc.y += (v0.y + v1.y) + (v2.y + v3.y);
        acc.z += (v0.z + v1.z) + (v2.z + v3.z);
        acc.w += (v0.w + v1.w) + (v2.w + v3.w);
    }
    for (; j < dc; ++j) {
        int s = bkt[j];
        f4 v = *reinterpret_cast<const f4*>(&g1[(size_t)s * HID + fo]);
        acc.x += v.x; acc.y += v.y; acc.z += v.z; acc.w += v.w;
    }
    int no = *ovfc; no = no < OVF_CAP ? no : OVF_CAP;
    for (int k = 0; k < no; ++k) {           // expected 0 iterations
        if (ovf[2 * k + 1] == i) {
            int s = ovf[2 * k];
            f4 v = *reinterpret_cast<const f4*>(&g1[(size_t)s * HID + fo]);
            acc.x += v.x; acc.y += v.y; acc.z += v.z; acc.w += v.w;
        }
    }
    float dv = dinv[i];
    f4 bb = *reinterpret_cast<const f4*>(&b1[fo]);
    float a0 = fmaxf(dv * acc.x + bb.x, 0.f);
    float a1 = fmaxf(dv * acc.y + bb.y, 0.f);
    float a2 = fmaxf(dv * acc.z + bb.z, 0.f);
    float a3 = fmaxf(dv * acc.w + bb.w, 0.f);
    int c0 = L * 4;
    float p[NCLS];
    #pragma unroll
    for (int jj = 0; jj < NCLS; ++jj)
        p[jj] = a0 * sW2[(c0 + 0) * NCLS + jj] + a1 * sW2[(c0 + 1) * NCLS + jj]
              + a2 * sW2[(c0 + 2) * NCLS + jj] + a3 * sW2[(c0 + 3) * NCLS + jj];
    #pragma unroll
    for (int jj = 0; jj < NCLS; ++jj) {
        p[jj] += __shfl_xor(p[jj], 1, 64);
        p[jj] += __shfl_xor(p[jj], 2, 64);
    }
    float* gp = &g2[(size_t)i * G2S];
    if (L == 0)
        *reinterpret_cast<f4*>(gp) = make_float4(dv * p[0], dv * p[1], dv * p[2], dv * p[3]);
    else if (L == 1)
        *reinterpret_cast<f4*>(gp + 4) = make_float4(dv * p[4], dv * p[5], dv * p[6], dv * p[7]);
    else if (L == 2)
        *reinterpret_cast<f4*>(gp + 8) = make_float4(dv * p[8], dv * p[9], 0.f, 0.f);
}

// ---------------- layer-2 aggregation + final epilogue ----------------
__global__ void k_agg2f(const int* __restrict__ cnt, const int* __restrict__ csr,
                        const float* __restrict__ g2, const float* __restrict__ dinv,
                        const float* __restrict__ b2,
                        const int* __restrict__ ovfc, const int* __restrict__ ovf,
                        float* __restrict__ out, int n)
{
    int tid = blockIdx.x * blockDim.x + threadIdx.x;
    int i = tid >> 2, L = tid & 3;
    if (i >= n || L >= 3) return;
    size_t fo = (size_t)L * 4;
    f4 acc = *reinterpret_cast<const f4*>(&g2[(size_t)i * G2S + fo]);  // self-loop
    int d = cnt[i];
    int dc = d < CAP ? d : CAP;
    const int* bkt = &csr[(size_t)i << CAPW];
    int j = 0;
    for (; j + 4 <= dc; j += 4) {
        int4 sv = *reinterpret_cast<const int4*>(bkt + j);
        f4 v0 = *reinterpret_cast<const f4*>(&g2[(size_t)sv.x * G2S + fo]);
        f4 v1 = *reinterpret_cast<const f4*>(&g2[(size_t)sv.y * G2S + fo]);
        f4 v2 = *reinterpret_cast<const f4*>(&g2[(size_t)sv.z * G2S + fo]);
        f4 v3 = *reinterpret_cast<const f4*>(&g2[(size_t)sv.w * G2S + fo]);
        acc.x += (v0.x + v1.x) + (v2.x + v3.x);
        acc.y += (v0.y + v1.y) + (v2.y + v3.y);
        acc.z += (v0.z + v1.z) + (v2.z + v3.z);
        acc.w += (v0.w + v1.w) + (v2.w + v3.w);
    }
    for (; j < dc; ++j) {
        int s = bkt[j];
        f4 v = *reinterpret_cast<const f4*>(&g2[(size_t)s * G2S + fo]);
        acc.x += v.x; acc.y += v.y; acc.z += v.z; acc.w += v.w;
    }
    int no = *ovfc; no = no < OVF_CAP ? no : OVF_CAP;
    for (int k = 0; k < no; ++k) {           // expected 0 iterations
        if (ovf[2 * k + 1] == i) {
            int s = ovf[2 * k];
            f4 v = *reinterpret_cast<const f4*>(&g2[(size_t)s * G2S + fo]);
            acc.x += v.x; acc.y += v.y; acc.z += v.z; acc.w += v.w;
        }
    }
    float dv = dinv[i];
    int c0 = L * 4;
    if (L < 2) {
        float2 w01 = make_float2(dv * acc.x + b2[c0], dv * acc.y + b2[c0 + 1]);
        float2 w23 = make_float2(dv * acc.z + b2[c0 + 2], dv * acc.w + b2[c0 + 3]);
        *reinterpret_cast<float2*>(&out[(size_t)i * NCLS + c0]) = w01;
        *reinterpret_cast<float2*>(&out[(size_t)i * NCLS + c0 + 2]) = w23;
    } else {
        float2 w01 = make_float2(dv * acc.x + b2[8], dv * acc.y + b2[9]);
        *reinterpret_cast<float2*>(&out[(size_t)i * NCLS + 8]) = w01;
    }
}

extern "C" void kernel_launch(void* const* d_in, const int* in_sizes, int n_in,
                              void* d_out, int out_size, void* d_ws, size_t ws_size,
                              hipStream_t stream) {
    const float* x  = (const float*)d_in[0];
    const int*   ei = (const int*)d_in[1];
    const float* W1 = (const float*)d_in[2];
    const float* b1 = (const float*)d_in[3];
    const float* W2 = (const float*)d_in[4];
    const float* b2 = (const float*)d_in[5];
    float* out = (float*)d_out;

    const int n = in_sizes[0] / N_FEAT;   // 100000
    const int E = in_sizes[1] / 2;        // 3200000

    char* ws = (char*)d_ws;
    size_t off = 0;
    auto alloc = [&](size_t bytes) -> void* {
        void* p = ws + off;
        off = (off + bytes + 255) & ~(size_t)255;
        return p;
    };
    int*   cnt  = (int*)alloc((size_t)n * 4);
    int*   ovfc = (int*)alloc(4);
    int*   csr  = (int*)alloc((size_t)n * CAP * 4);   // 25.6 MB
    int*   ovf  = (int*)alloc((size_t)OVF_CAP * 2 * 4);
    float* dinv = (float*)alloc((size_t)n * 4);
    float* g1   = (float*)alloc((size_t)n * HID * 4);
    float* g2   = (float*)alloc((size_t)n * G2S * 4);

    dim3 blk(256);
    int nb_n = (n + 255) / 256;
    int nb_f = (E + 1023) / 1024;
    int nb_a = (n * 4 + 255) / 256;

    hipMemsetAsync(cnt, 0, (size_t)n * 4, stream);
    hipMemsetAsync(ovfc, 0, 4, stream);
    k_fill<<<nb_f, blk, 0, stream>>>(ei, cnt, csr, ovfc, ovf, E);
    k_dinv<<<nb_n, blk, 0, stream>>>(cnt, dinv, n);
    k_gemm1<<<nb_n, blk, 0, stream>>>(x, W1, dinv, g1, n);
    k_aggmid<<<nb_a, blk, 0, stream>>>(cnt, csr, g1, dinv, b1, W2, ovfc, ovf, g2, n);
    k_agg2f<<<nb_a, blk, 0, stream>>>(cnt, csr, g2, dinv, b2, ovfc, ovf, out, n);
}